// Round 11
// baseline (103.362 us; speedup 1.0000x reference)
//
#include <hip/hip_runtime.h>

typedef unsigned short u16;
typedef short short8 __attribute__((ext_vector_type(8)));
typedef float f32x4 __attribute__((ext_vector_type(4)));

#define SLEN 2048
#define QKV_LD 3072
#define KOFF 2048
#define VOFF 2560

__device__ __forceinline__ u16 f2b(float f){
  unsigned u = __float_as_uint(f);
  u = u + 0x7FFFu + ((u >> 16) & 1u);     // RNE f32 -> bf16
  return (u16)(u >> 16);
}
__device__ __forceinline__ float b2f(u16 v){
  unsigned u = ((unsigned)v) << 16;
  return __uint_as_float(u);
}

__device__ __forceinline__ void gload16(const u16* g, u16* l){
  __builtin_amdgcn_global_load_lds((const __attribute__((address_space(1))) void*)g,
                                   (__attribute__((address_space(3))) void*)l, 16, 0, 0);
}

// ---------------- fused prep: rope table (b<128) + Wq/Wk/Wv transposes.
// R11: hidden f2b pass DELETED (48MB traffic) — QKV GEMM now reads hidden f32
// directly with reg-staged convert. Wo transpose lives in k_attn tail (R9).
__global__ __launch_bounds__(256) void k_prep(const int* __restrict__ pos, float* __restrict__ g,
                                              const float* __restrict__ Wq, const float* __restrict__ Wk,
                                              const float* __restrict__ Wv,
                                              u16* __restrict__ Wcat){
  __shared__ float tile[64][68];
  int b = blockIdx.x, t = threadIdx.x;
  if (b < 128){
    int idx = b * 256 + t;
    int s = idx >> 4, i = idx & 15;
    float inv = 1.0f / powf(150000.0f, (float)i / 16.0f);
    float wl = 6.283185307179586f / inv;
    float ratio = 4096.0f / wl;
    float alpha = (32.0f * ratio - 32.0f) / (1.0f - 32.0f);
    alpha = fminf(fmaxf(alpha, 0.0f), 1.0f);
    float invs = inv / powf(32.0f, alpha);
    float th = (float)pos[s] * invs;
    double tt = (double)th;
    g[idx] = (float)(cos(tt) + sin(tt));
    return;
  }
  b -= 128;
  const float* W; int Nw, rowoff;
  if (b < 1024)      { W = Wq; Nw = 2048; rowoff = 0; }
  else if (b < 1280) { W = Wk; Nw = 512;  rowoff = 2048; b -= 1024; }
  else               { W = Wv; Nw = 512;  rowoff = 2560; b -= 1280; }
  const int kt = b & 31, nt = b >> 5;
  const int k0 = kt * 64, n0 = nt * 64;
  #pragma unroll
  for (int i = 0; i < 4; ++i){
    int slot = i * 256 + t;
    int r = slot >> 4, c4 = (slot & 15) * 4;
    float4 v = *(const float4*)&W[(size_t)(k0 + r) * Nw + n0 + c4];
    tile[r][c4] = v.x; tile[r][c4+1] = v.y; tile[r][c4+2] = v.z; tile[r][c4+3] = v.w;
  }
  __syncthreads();
  #pragma unroll
  for (int i = 0; i < 4; ++i){
    int slot = i * 256 + t;
    int nl = slot >> 4, k4 = (slot & 15) * 4;
    ushort4 o;
    o.x = f2b(tile[k4][nl]);   o.y = f2b(tile[k4+1][nl]);
    o.z = f2b(tile[k4+2][nl]); o.w = f2b(tile[k4+3][nl]);
    *(ushort4*)&Wcat[(size_t)(rowoff + n0 + nl) * 2048 + k0 + k4] = o;
  }
}

// ---------------- GEMM: parameterized BMxBN block, BK=64, 4 waves (2x2 wave grid),
// XOR-8 source-side swizzle, XCD swizzle, 512-block grids = 2 blocks/CU.
// Single-barrier per K-step in all paths (R9/R10-validated).
//   QKV (AF32=1, NBUF=2, BM128xBN96): A read from hidden f32, reg-staged with f2b
//     convert (forced reg-staging — conversion impossible with gload_lds). Schedule:
//     issue B-gload_lds(k+1) + A-f32-loads(k+1) -> compute(k) -> vmcnt(0) ->
//     cvt+ds_write A(k+1) -> lgkmcnt(0) -> barrier. Hazards: RAW A via lgkm-drain
//     pre-barrier, RAW B via vmcnt-drain pre-barrier; WAR: buf^1 writes are
//     post-barrier@k-1, whose readers drained pre-barrier@k-1. LDS dest replicates
//     gload_lds's linear base+lane*16B; source swizzle unchanged.
//   out (AF32=0, NBUF=3, BM64xBN128): R9-validated rotation, counted vmcnt.
template<int OUTF32, int ROPE, int BM, int BN, int MINW, int NBUF, int AF32>
__global__ __launch_bounds__(256, MINW) void k_gemm(const u16* __restrict__ A, const float* __restrict__ Af,
                                                    const u16* __restrict__ Bt,
                                                    void* __restrict__ C, const float* __restrict__ g,
                                                    int M, int N, int K){
  constexpr int AG = BM / 32;               // A stage groups per wave
  constexpr int BG = BN / 32;               // B gload_lds per wave per stage
  constexpr int ASZ = BM * 64;              // u16 per A buffer
  constexpr int BSZ = BN * 64;              // u16 per B buffer
  constexpr int MR = BM / 32;               // 16-row fragments per wave tile
  constexpr int NR = BN / 32;               // 16-col fragments per wave tile
  __shared__ __align__(16) u16 Smem[NBUF * (ASZ + BSZ)];
  const int tid = threadIdx.x;
  const int lane = tid & 63;
  const int w = tid >> 6;                   // 0..3
  const int wr = (w >> 1) * (BM / 2);
  const int wc = (w & 1) * (BN / 2);

  const int nbx = M / BM;
  const int nb  = nbx * (N / BN);
  const int q8  = nb >> 3;
  const int bo  = blockIdx.x;
  const int id2 = (bo & 7) * q8 + (bo >> 3);
  const int m0 = (id2 % nbx) * BM;
  const int n0 = (id2 / nbx) * BN;

  const int rl = lane >> 3;
  const int sc = ((lane & 7) ^ rl) << 3;
  const u16* Ag[AG]; const u16* Bg[BG];
  int Ad[AG], Bd[BG];
  #pragma unroll
  for (int i = 0; i < AG; ++i){
    int row0 = w * (AG * 8) + i * 8;        // A rows 0..BM-1 across 4 waves
    if constexpr (!AF32) Ag[i] = A + (size_t)(m0 + row0 + rl) * K + sc;
    Ad[i] = row0 * 64;
  }
  #pragma unroll
  for (int i = 0; i < BG; ++i){
    int row0 = w * (BG * 8) + i * 8;        // B rows 0..BN-1 across 4 waves
    Bg[i] = Bt + (size_t)(n0 + row0 + rl) * K + sc;
    Bd[i] = NBUF * ASZ + row0 * 64;
  }

  const int fr = lane & 15;
  const int g4 = lane >> 4;

  f32x4 acc[MR][NR] = {};

  auto stageB = [&](int buf, int k0){
    #pragma unroll
    for (int i = 0; i < BG; ++i) gload16(Bg[i] + k0, Smem + Bd[i] + buf * BSZ);
  };

  auto compute = [&](int buf){
    const u16* Asb = Smem + buf * ASZ;
    const u16* Bsb = Smem + NBUF * ASZ + buf * BSZ;
    #pragma unroll
    for (int kk = 0; kk < 2; ++kk){
      const int sw = (((kk * 4 + g4)) ^ (fr & 7)) << 3;
      short8 af[MR], bf[NR];
      #pragma unroll
      for (int m = 0; m < MR; ++m)
        af[m] = *(const short8*)&Asb[(wr + m * 16 + fr) * 64 + sw];
      #pragma unroll
      for (int j = 0; j < NR; ++j)
        bf[j] = *(const short8*)&Bsb[(wc + j * 16 + fr) * 64 + sw];
      #pragma unroll
      for (int m = 0; m < MR; ++m)
        #pragma unroll
        for (int j = 0; j < NR; ++j)
          acc[m][j] = __builtin_amdgcn_mfma_f32_16x16x32_bf16(af[m], bf[j], acc[m][j], 0, 0, 0);
    }
  };

  const int nt = K >> 6;
  if constexpr (AF32){
    // ---- QKV path: A reg-staged from f32 with convert, single barrier per K-step.
    float4 areg[AG][2];
    const float* Asrc[AG];
    #pragma unroll
    for (int i = 0; i < AG; ++i)
      Asrc[i] = Af + (size_t)(m0 + w * (AG * 8) + i * 8 + rl) * K + sc;
    auto loadA = [&](int k0){
      #pragma unroll
      for (int i = 0; i < AG; ++i){
        areg[i][0] = *(const float4*)(Asrc[i] + k0);
        areg[i][1] = *(const float4*)(Asrc[i] + k0 + 4);
      }
    };
    auto writeA = [&](int buf){
      #pragma unroll
      for (int i = 0; i < AG; ++i){
        short8 o;
        o[0] = (short)f2b(areg[i][0].x); o[1] = (short)f2b(areg[i][0].y);
        o[2] = (short)f2b(areg[i][0].z); o[3] = (short)f2b(areg[i][0].w);
        o[4] = (short)f2b(areg[i][1].x); o[5] = (short)f2b(areg[i][1].y);
        o[6] = (short)f2b(areg[i][1].z); o[7] = (short)f2b(areg[i][1].w);
        *(short8*)&Smem[Ad[i] + buf * ASZ + lane * 8] = o;
      }
    };
    stageB(0, 0); loadA(0);
    asm volatile("s_waitcnt vmcnt(0)" ::: "memory");
    writeA(0);
    asm volatile("s_waitcnt lgkmcnt(0)" ::: "memory");
    __builtin_amdgcn_s_barrier();
    int buf = 0;
    for (int kt = 0; kt < nt; ++kt){
      __builtin_amdgcn_sched_barrier(0);
      if (kt + 1 < nt){ stageB(buf ^ 1, (kt + 1) << 6); loadA((kt + 1) << 6); }
      compute(buf);
      if (kt + 1 < nt){
        asm volatile("s_waitcnt vmcnt(0)" ::: "memory");   // A-regs + B-lds (k+1) landed
        writeA(buf ^ 1);
        asm volatile("s_waitcnt lgkmcnt(0)" ::: "memory"); // A ds_writes drained
        __builtin_amdgcn_s_barrier();                      // publish buf^1
      }
      buf ^= 1;
    }
  } else {
    // ---- out path: NBUF=3 rotation, stage-before-barrier, counted vmcnt (R9).
    auto stage = [&](int buf, int k0){
      #pragma unroll
      for (int i = 0; i < AG; ++i) gload16(Ag[i] + k0, Smem + Ad[i] + buf * ASZ);
      stageB(buf, k0);
    };
    stage(0, 0);
    int buf = 0;
    for (int kt = 0; kt < nt; ++kt){
      int nxt = (buf + 1 == NBUF) ? 0 : buf + 1;
      if (kt + 1 < nt){
        stage(nxt, (kt + 1) << 6);
        if constexpr (AG + BG == 6)      asm volatile("s_waitcnt vmcnt(6)" ::: "memory");
        else if constexpr (AG + BG == 7) asm volatile("s_waitcnt vmcnt(7)" ::: "memory");
        else                             asm volatile("s_waitcnt vmcnt(8)" ::: "memory");
      } else {
        asm volatile("s_waitcnt vmcnt(0)" ::: "memory");
      }
      __builtin_amdgcn_s_barrier();
      __builtin_amdgcn_sched_barrier(0);
      compute(buf);
      buf = nxt;
    }
  }

  const int r4 = g4 * 4;
  #pragma unroll
  for (int m = 0; m < MR; ++m)
    #pragma unroll
    for (int j = 0; j < NR; ++j)
      #pragma unroll
      for (int v = 0; v < 4; ++v){
        size_t row = (size_t)(m0 + wr + m * 16 + r4 + v);
        size_t col = (size_t)(n0 + wc + j * 16 + fr);
        float x = acc[m][j][v];
        if (OUTF32){
          ((float*)C)[row * N + col] = x;
        } else {
          if (ROPE){
            int c = (int)col;
            int cj = c & 63;
            if (c < 2560 && cj < 32) x *= g[row * 16 + (cj >> 1)];
            if (c < 2048) x *= 0.18033688f;   // 0.125 * log2(e): softmax uses exp2 directly
          }
          ((u16*)C)[row * N + col] = f2b(x);
        }
      }
}

// ---------------- windowed attention, R9-validated: R7 structure (full P, single
// PV phase, late barrier, setprio, exp2-direct) + Wo-transpose tail.
#define PST 168
__global__ __launch_bounds__(512, 4) void k_attn(const u16* __restrict__ qkv, u16* __restrict__ aout,
                                                 const float* __restrict__ Wo, u16* __restrict__ Wot){
  __shared__ __align__(16) u16 Vt[64 * 264];    // Vt[d][ck], 256 keys, ck = kk ^ ((d>>4)<<3)
  __shared__ __align__(16) u16 P[8 * 16 * PST]; // per-wave 16-row slices
  const int tid = threadIdx.x;
  const int lane = tid & 63;
  const int w = tid >> 6;                      // 0..7
  const int id = blockIdx.x;                   // 0..511
  const int id2 = (id & 7) * 64 + (id >> 3);   // XCD x (id%8) -> contiguous chunk
  const int h = id2 >> 4;                      // head 0..31 (XCD x -> heads 4x..4x+3)
  const int q0 = (id2 & 15) * 128;             // q-block start
  const int kvh = h >> 2;                      // == id & 7
  const int kv0 = q0 - 128;                    // Vt column 0 = this key

  { // stage V transposed: 64 d x 256 kk, column-swizzled (4 iters x 512 threads).
    // No barrier here — writes drain under QK/softmax; barrier is before PV.
    const u16* Vg = qkv + VOFF + kvh * 64;
    #pragma unroll
    for (int i = 0; i < 4; ++i){
      int slot = i * 512 + tid;
      int kk = slot >> 3, d8 = (slot & 7) * 8;
      int ks = kv0 + kk; if (ks < 0) ks = 0;
      int ck = kk ^ ((d8 >> 4) << 3);          // d8..d8+7 share the same d>>4 block
      short8 v = *(const short8*)(Vg + (size_t)ks * QKV_LD + d8);
      #pragma unroll
      for (int e = 0; e < 8; ++e) Vt[(d8 + e) * 264 + ck] = (u16)v[e];
    }
  }

  const int fr = lane & 15;
  const int kc8 = (lane >> 4) * 8;
  const int r4 = (lane >> 4) * 4;
  const int tt = w >> 2;                       // which 64-row q-tile (0/1)
  const int wl = w & 3;                        // wave-in-tile 0..3
  const int nw0 = wl & ~1;                     // per-wave 32-aligned key-tile window
  const int c0 = nw0 * 16;
  const int qt = q0 + tt * 64;                 // this tile's first q row
  const int kbase = qt - 128;                  // tile-local key 0
  u16* Pw = P + w * 16 * PST;                  // this wave's P slice
  const u16* Qg = qkv + h * 64;
  const u16* Kg = qkv + KOFF + kvh * 64;

  short8 qa[2];
  {
    int qrow = qt + wl * 16 + fr;
    qa[0] = *(const short8*)(Qg + (size_t)qrow * QKV_LD + kc8);
    qa[1] = *(const short8*)(Qg + (size_t)qrow * QKV_LD + 32 + kc8);
  }

  f32x4 sc[10];
  __builtin_amdgcn_s_setprio(1);
  #pragma unroll
  for (int n = 0; n < 10; ++n){
    int kr = kbase + (nw0 + n) * 16 + fr;
    int krc = kr < 0 ? 0 : kr;
    short8 kb0 = *(const short8*)(Kg + (size_t)krc * QKV_LD + kc8);
    short8 kb1 = *(const short8*)(Kg + (size_t)krc * QKV_LD + 32 + kc8);
    f32x4 z = {0.f, 0.f, 0.f, 0.f};
    z = __builtin_amdgcn_mfma_f32_16x16x32_bf16(qa[0], kb0, z, 0, 0, 0);
    z = __builtin_amdgcn_mfma_f32_16x16x32_bf16(qa[1], kb1, z, 0, 0, 0);
    sc[n] = z;
  }
  __builtin_amdgcn_s_setprio(0);

  float inv_l[4];
  #pragma unroll
  for (int j = 0; j < 4; ++j){
    int q = qt + wl * 16 + r4 + j;
    float mx = -3.0e38f;
    #pragma unroll
    for (int n = 0; n < 10; ++n){
      int key = kbase + (nw0 + n) * 16 + fr;
      bool valid = (key >= 0) && (key <= q) && (key >= q - 128);
      float s = valid ? sc[n][j] : -1.0e30f;
      sc[n][j] = s;
      mx = fmaxf(mx, s);
    }
    mx = fmaxf(mx, __shfl_xor(mx, 1));
    mx = fmaxf(mx, __shfl_xor(mx, 2));
    mx = fmaxf(mx, __shfl_xor(mx, 4));
    mx = fmaxf(mx, __shfl_xor(mx, 8));
    float sum = 0.f;
    #pragma unroll
    for (int n = 0; n < 10; ++n){
      float pp = exp2f(sc[n][j] - mx);         // scores pre-scaled by log2e in GEMM
      sc[n][j] = pp;
      sum += pp;
    }
    sum += __shfl_xor(sum, 1);
    sum += __shfl_xor(sum, 2);
    sum += __shfl_xor(sum, 4);
    sum += __shfl_xor(sum, 8);
    inv_l[j] = 1.0f / sum;
  }

  #pragma unroll
  for (int n = 0; n < 10; ++n)
    #pragma unroll
    for (int j = 0; j < 4; ++j)
      Pw[(r4 + j) * PST + n * 16 + fr] = f2b(sc[n][j]);

  // Drain this wave's P-writes AND V-staging writes (same lgkm counter), then
  // cross-wave barrier so every wave's Vt contribution is visible before PV.
  asm volatile("s_waitcnt lgkmcnt(0)" ::: "memory");
  __syncthreads();

  f32x4 ov[4] = {};
  __builtin_amdgcn_s_setprio(1);
  #pragma unroll
  for (int kc = 0; kc < 5; ++kc){
    short8 pa = *(const short8*)&Pw[fr * PST + kc * 32 + kc8];
    #pragma unroll
    for (int f = 0; f < 4; ++f){
      short8 vb = *(const short8*)&Vt[(f * 16 + fr) * 264 + tt * 64 + c0 + kc * 32 + (kc8 ^ (f << 3))];
      ov[f] = __builtin_amdgcn_mfma_f32_16x16x32_bf16(pa, vb, ov[f], 0, 0, 0);
    }
  }
  __builtin_amdgcn_s_setprio(0);

  #pragma unroll
  for (int f = 0; f < 4; ++f)
    #pragma unroll
    for (int j = 0; j < 4; ++j){
      int q = qt + wl * 16 + r4 + j;
      int col = h * 64 + f * 16 + fr;
      aout[(size_t)q * 2048 + col] = f2b(ov[f][j] * inv_l[j]);
    }

  // ---- Wo-transpose tail: 2 of 1024 64x64 tiles per block, LDS reused from Vt.
  __syncthreads();                             // all waves done reading Vt/P
  float (*tf)[68] = (float(*)[68])Vt;          // 17.4KB <= 33.8KB
  #pragma unroll
  for (int tix = 0; tix < 2; ++tix){
    int tile = id * 2 + tix;
    int kt2 = tile & 31, nt2 = tile >> 5;
    int k0 = kt2 * 64, n0 = nt2 * 64;
    #pragma unroll
    for (int i = 0; i < 2; ++i){
      int slot = i * 512 + tid;
      int r = slot >> 4, c4 = (slot & 15) * 4;
      float4 v = *(const float4*)&Wo[(size_t)(k0 + r) * 2048 + n0 + c4];
      tf[r][c4] = v.x; tf[r][c4+1] = v.y; tf[r][c4+2] = v.z; tf[r][c4+3] = v.w;
    }
    __syncthreads();
    #pragma unroll
    for (int i = 0; i < 2; ++i){
      int slot = i * 512 + tid;
      int nl = slot >> 4, k4 = (slot & 15) * 4;
      ushort4 o;
      o.x = f2b(tf[k4][nl]);   o.y = f2b(tf[k4+1][nl]);
      o.z = f2b(tf[k4+2][nl]); o.w = f2b(tf[k4+3][nl]);
      *(ushort4*)&Wot[(size_t)(n0 + nl) * 2048 + k0 + k4] = o;
    }
    __syncthreads();
  }
}

extern "C" void kernel_launch(void* const* d_in, const int* in_sizes, int n_in,
                              void* d_out, int out_size, void* d_ws, size_t ws_size,
                              hipStream_t stream) {
  const float* hidden = (const float*)d_in[0];
  const int*   pos    = (const int*)d_in[1];
  const float* Wq     = (const float*)d_in[2];
  const float* Wk     = (const float*)d_in[3];
  const float* Wv     = (const float*)d_in[4];
  const float* Wo     = (const float*)d_in[5];
  float* out = (float*)d_out;
  char* ws = (char*)d_ws;

  u16*  aout = (u16*)(ws);                           // 8 MB attn output
  u16*  Wcat = (u16*)(ws + ((size_t)8 << 20));       // 12 MB [Wq^T;Wk^T;Wv^T], LD=2048
  u16*  Wot  = (u16*)(ws + ((size_t)20 << 20));      // 8 MB Wo^T (written by k_attn tail)
  u16*  QKV  = (u16*)(ws + ((size_t)28 << 20));      // 12 MB
  float* gtab = (float*)(ws + ((size_t)40 << 20));   // 128 KB rope factors

  k_prep<<<1664, 256, 0, stream>>>(pos, gtab, Wq, Wk, Wv, Wcat);
  k_gemm<0,1,128,96,2,2,1><<<512, 256, 0, stream>>>(nullptr, hidden, Wcat, QKV, gtab, 2048, 3072, 2048);
  k_attn<<<512, 512, 0, stream>>>(QKV, aout, Wo, Wot);
  k_gemm<1,0,64,128,2,3,0><<<512, 256, 0, stream>>>(aout, nullptr, Wot, out, nullptr, 2048, 2048, 2048);
}

// Round 12
// 93.096 us; speedup vs baseline: 1.1103x; 1.1103x over previous
//
#include <hip/hip_runtime.h>

typedef unsigned short u16;
typedef short short8 __attribute__((ext_vector_type(8)));
typedef float f32x4 __attribute__((ext_vector_type(4)));

#define SLEN 2048
#define QKV_LD 3072
#define KOFF 2048
#define VOFF 2560

__device__ __forceinline__ u16 f2b(float f){
  unsigned u = __float_as_uint(f);
  u = u + 0x7FFFu + ((u >> 16) & 1u);     // RNE f32 -> bf16
  return (u16)(u >> 16);
}
__device__ __forceinline__ float b2f(u16 v){
  unsigned u = ((unsigned)v) << 16;
  return __uint_as_float(u);
}

__device__ __forceinline__ void gload16(const u16* g, u16* l){
  __builtin_amdgcn_global_load_lds((const __attribute__((address_space(1))) void*)g,
                                   (__attribute__((address_space(3))) void*)l, 16, 0, 0);
}

// ---------------- fused prep: hidden f2b (b<4096) + rope table (4096..4223) +
// Wq/Wk/Wv transposes. Wo transpose lives in k_attn tail (R9).
// R11 lesson: the hidden f2b pre-pass is the RIGHT place for conversion —
// folding it into QKV A-staging (reg-staged f32) cost +20us (FETCH 39->72MB,
// serial cvt/ds_write chain per K-step). Keep the separate BW-bound pass.
__global__ __launch_bounds__(256) void k_prep(const float* __restrict__ hidden, u16* __restrict__ hb,
                                              const int* __restrict__ pos, float* __restrict__ g,
                                              const float* __restrict__ Wq, const float* __restrict__ Wk,
                                              const float* __restrict__ Wv,
                                              u16* __restrict__ Wcat){
  __shared__ float tile[64][68];
  int b = blockIdx.x, t = threadIdx.x;
  if (b < 4096){
    int i = b * 256 + t;
    float4 v = ((const float4*)hidden)[i];
    ushort4 o;
    o.x = f2b(v.x); o.y = f2b(v.y); o.z = f2b(v.z); o.w = f2b(v.w);
    ((ushort4*)hb)[i] = o;
    return;
  }
  if (b < 4224){
    int idx = (b - 4096) * 256 + t;
    int s = idx >> 4, i = idx & 15;
    float inv = 1.0f / powf(150000.0f, (float)i / 16.0f);
    float wl = 6.283185307179586f / inv;
    float ratio = 4096.0f / wl;
    float alpha = (32.0f * ratio - 32.0f) / (1.0f - 32.0f);
    alpha = fminf(fmaxf(alpha, 0.0f), 1.0f);
    float invs = inv / powf(32.0f, alpha);
    float th = (float)pos[s] * invs;
    double tt = (double)th;
    g[idx] = (float)(cos(tt) + sin(tt));
    return;
  }
  b -= 4224;
  const float* W; int Nw, rowoff;
  if (b < 1024)      { W = Wq; Nw = 2048; rowoff = 0; }
  else if (b < 1280) { W = Wk; Nw = 512;  rowoff = 2048; b -= 1024; }
  else               { W = Wv; Nw = 512;  rowoff = 2560; b -= 1280; }
  const int kt = b & 31, nt = b >> 5;
  const int k0 = kt * 64, n0 = nt * 64;
  #pragma unroll
  for (int i = 0; i < 4; ++i){
    int slot = i * 256 + t;
    int r = slot >> 4, c4 = (slot & 15) * 4;
    float4 v = *(const float4*)&W[(size_t)(k0 + r) * Nw + n0 + c4];
    tile[r][c4] = v.x; tile[r][c4+1] = v.y; tile[r][c4+2] = v.z; tile[r][c4+3] = v.w;
  }
  __syncthreads();
  #pragma unroll
  for (int i = 0; i < 4; ++i){
    int slot = i * 256 + t;
    int nl = slot >> 4, k4 = (slot & 15) * 4;
    ushort4 o;
    o.x = f2b(tile[k4][nl]);   o.y = f2b(tile[k4+1][nl]);
    o.z = f2b(tile[k4+2][nl]); o.w = f2b(tile[k4+3][nl]);
    *(ushort4*)&Wcat[(size_t)(rowoff + n0 + nl) * 2048 + k0 + k4] = o;
  }
}

// ---------------- GEMM: parameterized BMxBN block, BK=64, 4 waves (2x2 wave grid),
// gload_lds-16B, XOR-8 source-side swizzle, XCD swizzle. 512-block grids = 2/CU.
// Both paths single-barrier per K-step (R9/R10-validated):
//   NBUF=2 (QKV, BM128xBN96, 57.3KB): stage AFTER the barrier:
//     iter k: vmcnt(0) -> barrier -> stage(k+1) -> compute(k)
//   NBUF=3 (out, BM64xBN128, 73.7KB): rotation, stage-before-barrier, counted vmcnt.
template<int OUTF32, int ROPE, int BM, int BN, int MINW, int NBUF>
__global__ __launch_bounds__(256, MINW) void k_gemm(const u16* __restrict__ A, const u16* __restrict__ Bt,
                                                    void* __restrict__ C, const float* __restrict__ g,
                                                    int M, int N, int K){
  constexpr int AG = BM / 32;               // A gload_lds per wave per stage
  constexpr int BG = BN / 32;               // B gload_lds per wave per stage
  constexpr int ASZ = BM * 64;              // u16 per A buffer
  constexpr int BSZ = BN * 64;              // u16 per B buffer
  constexpr int MR = BM / 32;               // 16-row fragments per wave tile
  constexpr int NR = BN / 32;               // 16-col fragments per wave tile
  __shared__ __align__(16) u16 Smem[NBUF * (ASZ + BSZ)];
  const int tid = threadIdx.x;
  const int lane = tid & 63;
  const int w = tid >> 6;                   // 0..3
  const int wr = (w >> 1) * (BM / 2);
  const int wc = (w & 1) * (BN / 2);

  const int nbx = M / BM;
  const int nb  = nbx * (N / BN);
  const int q8  = nb >> 3;
  const int bo  = blockIdx.x;
  const int id2 = (bo & 7) * q8 + (bo >> 3);
  const int m0 = (id2 % nbx) * BM;
  const int n0 = (id2 / nbx) * BN;

  const int rl = lane >> 3;
  const int sc = ((lane & 7) ^ rl) << 3;
  const u16* Ag[AG]; const u16* Bg[BG];
  int Ad[AG], Bd[BG];
  #pragma unroll
  for (int i = 0; i < AG; ++i){
    int row0 = w * (AG * 8) + i * 8;        // A rows 0..BM-1 across 4 waves
    Ag[i] = A + (size_t)(m0 + row0 + rl) * K + sc;
    Ad[i] = row0 * 64;
  }
  #pragma unroll
  for (int i = 0; i < BG; ++i){
    int row0 = w * (BG * 8) + i * 8;        // B rows 0..BN-1 across 4 waves
    Bg[i] = Bt + (size_t)(n0 + row0 + rl) * K + sc;
    Bd[i] = NBUF * ASZ + row0 * 64;
  }

  const int fr = lane & 15;
  const int g4 = lane >> 4;

  f32x4 acc[MR][NR] = {};

  auto stage = [&](int buf, int k0){
    #pragma unroll
    for (int i = 0; i < AG; ++i) gload16(Ag[i] + k0, Smem + Ad[i] + buf * ASZ);
    #pragma unroll
    for (int i = 0; i < BG; ++i) gload16(Bg[i] + k0, Smem + Bd[i] + buf * BSZ);
  };

  auto compute = [&](int buf){
    const u16* Asb = Smem + buf * ASZ;
    const u16* Bsb = Smem + NBUF * ASZ + buf * BSZ;
    #pragma unroll
    for (int kk = 0; kk < 2; ++kk){
      const int sw = (((kk * 4 + g4)) ^ (fr & 7)) << 3;
      short8 af[MR], bf[NR];
      #pragma unroll
      for (int m = 0; m < MR; ++m)
        af[m] = *(const short8*)&Asb[(wr + m * 16 + fr) * 64 + sw];
      #pragma unroll
      for (int j = 0; j < NR; ++j)
        bf[j] = *(const short8*)&Bsb[(wc + j * 16 + fr) * 64 + sw];
      #pragma unroll
      for (int m = 0; m < MR; ++m)
        #pragma unroll
        for (int j = 0; j < NR; ++j)
          acc[m][j] = __builtin_amdgcn_mfma_f32_16x16x32_bf16(af[m], bf[j], acc[m][j], 0, 0, 0);
    }
  };

  stage(0, 0);
  int buf = 0;
  const int nt = K >> 6;
  if constexpr (NBUF == 2){
    for (int kt = 0; kt < nt; ++kt){
      asm volatile("s_waitcnt vmcnt(0)" ::: "memory");   // drain own stage(kt)
      __builtin_amdgcn_s_barrier();                      // all waves' stage(kt) visible
      __builtin_amdgcn_sched_barrier(0);
      if (kt + 1 < nt) stage(buf ^ 1, (kt + 1) << 6);    // WAR-safe: post-barrier
      compute(buf);
      buf ^= 1;
    }
  } else {
    for (int kt = 0; kt < nt; ++kt){
      int nxt = (buf + 1 == NBUF) ? 0 : buf + 1;
      if (kt + 1 < nt){
        stage(nxt, (kt + 1) << 6);
        if constexpr (AG + BG == 6)      asm volatile("s_waitcnt vmcnt(6)" ::: "memory");
        else if constexpr (AG + BG == 7) asm volatile("s_waitcnt vmcnt(7)" ::: "memory");
        else                             asm volatile("s_waitcnt vmcnt(8)" ::: "memory");
      } else {
        asm volatile("s_waitcnt vmcnt(0)" ::: "memory");
      }
      __builtin_amdgcn_s_barrier();
      __builtin_amdgcn_sched_barrier(0);
      compute(buf);
      buf = nxt;
    }
  }

  const int r4 = g4 * 4;
  #pragma unroll
  for (int m = 0; m < MR; ++m)
    #pragma unroll
    for (int j = 0; j < NR; ++j)
      #pragma unroll
      for (int v = 0; v < 4; ++v){
        size_t row = (size_t)(m0 + wr + m * 16 + r4 + v);
        size_t col = (size_t)(n0 + wc + j * 16 + fr);
        float x = acc[m][j][v];
        if (OUTF32){
          ((float*)C)[row * N + col] = x;
        } else {
          if (ROPE){
            int c = (int)col;
            int cj = c & 63;
            if (c < 2560 && cj < 32) x *= g[row * 16 + (cj >> 1)];
            if (c < 2048) x *= 0.18033688f;   // 0.125 * log2(e): softmax uses exp2 directly
          }
          ((u16*)C)[row * N + col] = f2b(x);
        }
      }
}

// ---------------- windowed attention, R9-validated: R7 structure (full P, single
// PV phase, late barrier, setprio, exp2-direct) + Wo-transpose tail.
#define PST 168
__global__ __launch_bounds__(512, 4) void k_attn(const u16* __restrict__ qkv, u16* __restrict__ aout,
                                                 const float* __restrict__ Wo, u16* __restrict__ Wot){
  __shared__ __align__(16) u16 Vt[64 * 264];    // Vt[d][ck], 256 keys, ck = kk ^ ((d>>4)<<3)
  __shared__ __align__(16) u16 P[8 * 16 * PST]; // per-wave 16-row slices
  const int tid = threadIdx.x;
  const int lane = tid & 63;
  const int w = tid >> 6;                      // 0..7
  const int id = blockIdx.x;                   // 0..511
  const int id2 = (id & 7) * 64 + (id >> 3);   // XCD x (id%8) -> contiguous chunk
  const int h = id2 >> 4;                      // head 0..31 (XCD x -> heads 4x..4x+3)
  const int q0 = (id2 & 15) * 128;             // q-block start
  const int kvh = h >> 2;                      // == id & 7
  const int kv0 = q0 - 128;                    // Vt column 0 = this key

  { // stage V transposed: 64 d x 256 kk, column-swizzled (4 iters x 512 threads).
    // No barrier here — writes drain under QK/softmax; barrier is before PV.
    const u16* Vg = qkv + VOFF + kvh * 64;
    #pragma unroll
    for (int i = 0; i < 4; ++i){
      int slot = i * 512 + tid;
      int kk = slot >> 3, d8 = (slot & 7) * 8;
      int ks = kv0 + kk; if (ks < 0) ks = 0;
      int ck = kk ^ ((d8 >> 4) << 3);          // d8..d8+7 share the same d>>4 block
      short8 v = *(const short8*)(Vg + (size_t)ks * QKV_LD + d8);
      #pragma unroll
      for (int e = 0; e < 8; ++e) Vt[(d8 + e) * 264 + ck] = (u16)v[e];
    }
  }

  const int fr = lane & 15;
  const int kc8 = (lane >> 4) * 8;
  const int r4 = (lane >> 4) * 4;
  const int tt = w >> 2;                       // which 64-row q-tile (0/1)
  const int wl = w & 3;                        // wave-in-tile 0..3
  const int nw0 = wl & ~1;                     // per-wave 32-aligned key-tile window
  const int c0 = nw0 * 16;
  const int qt = q0 + tt * 64;                 // this tile's first q row
  const int kbase = qt - 128;                  // tile-local key 0
  u16* Pw = P + w * 16 * PST;                  // this wave's P slice
  const u16* Qg = qkv + h * 64;
  const u16* Kg = qkv + KOFF + kvh * 64;

  short8 qa[2];
  {
    int qrow = qt + wl * 16 + fr;
    qa[0] = *(const short8*)(Qg + (size_t)qrow * QKV_LD + kc8);
    qa[1] = *(const short8*)(Qg + (size_t)qrow * QKV_LD + 32 + kc8);
  }

  f32x4 sc[10];
  __builtin_amdgcn_s_setprio(1);
  #pragma unroll
  for (int n = 0; n < 10; ++n){
    int kr = kbase + (nw0 + n) * 16 + fr;
    int krc = kr < 0 ? 0 : kr;
    short8 kb0 = *(const short8*)(Kg + (size_t)krc * QKV_LD + kc8);
    short8 kb1 = *(const short8*)(Kg + (size_t)krc * QKV_LD + 32 + kc8);
    f32x4 z = {0.f, 0.f, 0.f, 0.f};
    z = __builtin_amdgcn_mfma_f32_16x16x32_bf16(qa[0], kb0, z, 0, 0, 0);
    z = __builtin_amdgcn_mfma_f32_16x16x32_bf16(qa[1], kb1, z, 0, 0, 0);
    sc[n] = z;
  }
  __builtin_amdgcn_s_setprio(0);

  float inv_l[4];
  #pragma unroll
  for (int j = 0; j < 4; ++j){
    int q = qt + wl * 16 + r4 + j;
    float mx = -3.0e38f;
    #pragma unroll
    for (int n = 0; n < 10; ++n){
      int key = kbase + (nw0 + n) * 16 + fr;
      bool valid = (key >= 0) && (key <= q) && (key >= q - 128);
      float s = valid ? sc[n][j] : -1.0e30f;
      sc[n][j] = s;
      mx = fmaxf(mx, s);
    }
    mx = fmaxf(mx, __shfl_xor(mx, 1));
    mx = fmaxf(mx, __shfl_xor(mx, 2));
    mx = fmaxf(mx, __shfl_xor(mx, 4));
    mx = fmaxf(mx, __shfl_xor(mx, 8));
    float sum = 0.f;
    #pragma unroll
    for (int n = 0; n < 10; ++n){
      float pp = exp2f(sc[n][j] - mx);         // scores pre-scaled by log2e in GEMM
      sc[n][j] = pp;
      sum += pp;
    }
    sum += __shfl_xor(sum, 1);
    sum += __shfl_xor(sum, 2);
    sum += __shfl_xor(sum, 4);
    sum += __shfl_xor(sum, 8);
    inv_l[j] = 1.0f / sum;
  }

  #pragma unroll
  for (int n = 0; n < 10; ++n)
    #pragma unroll
    for (int j = 0; j < 4; ++j)
      Pw[(r4 + j) * PST + n * 16 + fr] = f2b(sc[n][j]);

  // Drain this wave's P-writes AND V-staging writes (same lgkm counter), then
  // cross-wave barrier so every wave's Vt contribution is visible before PV.
  asm volatile("s_waitcnt lgkmcnt(0)" ::: "memory");
  __syncthreads();

  f32x4 ov[4] = {};
  __builtin_amdgcn_s_setprio(1);
  #pragma unroll
  for (int kc = 0; kc < 5; ++kc){
    short8 pa = *(const short8*)&Pw[fr * PST + kc * 32 + kc8];
    #pragma unroll
    for (int f = 0; f < 4; ++f){
      short8 vb = *(const short8*)&Vt[(f * 16 + fr) * 264 + tt * 64 + c0 + kc * 32 + (kc8 ^ (f << 3))];
      ov[f] = __builtin_amdgcn_mfma_f32_16x16x32_bf16(pa, vb, ov[f], 0, 0, 0);
    }
  }
  __builtin_amdgcn_s_setprio(0);

  #pragma unroll
  for (int f = 0; f < 4; ++f)
    #pragma unroll
    for (int j = 0; j < 4; ++j){
      int q = qt + wl * 16 + r4 + j;
      int col = h * 64 + f * 16 + fr;
      aout[(size_t)q * 2048 + col] = f2b(ov[f][j] * inv_l[j]);
    }

  // ---- Wo-transpose tail: 2 of 1024 64x64 tiles per block, LDS reused from Vt.
  __syncthreads();                             // all waves done reading Vt/P
  float (*tf)[68] = (float(*)[68])Vt;          // 17.4KB <= 33.8KB
  #pragma unroll
  for (int tix = 0; tix < 2; ++tix){
    int tile = id * 2 + tix;
    int kt2 = tile & 31, nt2 = tile >> 5;
    int k0 = kt2 * 64, n0 = nt2 * 64;
    #pragma unroll
    for (int i = 0; i < 2; ++i){
      int slot = i * 512 + tid;
      int r = slot >> 4, c4 = (slot & 15) * 4;
      float4 v = *(const float4*)&Wo[(size_t)(k0 + r) * 2048 + n0 + c4];
      tf[r][c4] = v.x; tf[r][c4+1] = v.y; tf[r][c4+2] = v.z; tf[r][c4+3] = v.w;
    }
    __syncthreads();
    #pragma unroll
    for (int i = 0; i < 2; ++i){
      int slot = i * 512 + tid;
      int nl = slot >> 4, k4 = (slot & 15) * 4;
      ushort4 o;
      o.x = f2b(tf[k4][nl]);   o.y = f2b(tf[k4+1][nl]);
      o.z = f2b(tf[k4+2][nl]); o.w = f2b(tf[k4+3][nl]);
      *(ushort4*)&Wot[(size_t)(n0 + nl) * 2048 + k0 + k4] = o;
    }
    __syncthreads();
  }
}

extern "C" void kernel_launch(void* const* d_in, const int* in_sizes, int n_in,
                              void* d_out, int out_size, void* d_ws, size_t ws_size,
                              hipStream_t stream) {
  const float* hidden = (const float*)d_in[0];
  const int*   pos    = (const int*)d_in[1];
  const float* Wq     = (const float*)d_in[2];
  const float* Wk     = (const float*)d_in[3];
  const float* Wv     = (const float*)d_in[4];
  const float* Wo     = (const float*)d_in[5];
  float* out = (float*)d_out;
  char* ws = (char*)d_ws;

  u16*  hb   = (u16*)(ws);                           // 8 MB; reused as aout after QKV GEMM
  u16*  Wcat = (u16*)(ws + ((size_t)8 << 20));       // 12 MB [Wq^T;Wk^T;Wv^T], LD=2048
  u16*  Wot  = (u16*)(ws + ((size_t)20 << 20));      // 8 MB Wo^T (written by k_attn tail)
  u16*  QKV  = (u16*)(ws + ((size_t)28 << 20));      // 12 MB
  float* gtab = (float*)(ws + ((size_t)40 << 20));   // 128 KB rope factors
  u16*  aout = hb;

  k_prep<<<5760, 256, 0, stream>>>(hidden, hb, pos, gtab, Wq, Wk, Wv, Wcat);
  k_gemm<0,1,128,96,2,2><<<512, 256, 0, stream>>>(hb, Wcat, QKV, gtab, 2048, 3072, 2048);
  k_attn<<<512, 512, 0, stream>>>(QKV, aout, Wo, Wot);
  k_gemm<1,0,64,128,2,3><<<512, 256, 0, stream>>>(aout, Wot, out, nullptr, 2048, 2048, 2048);
}